// Round 8
// baseline (446.695 us; speedup 1.0000x reference)
//
#include <hip/hip_runtime.h>
#include <math.h>

#define NLEV 16
#define TBL  (1u << 19)
#define TMASK (TBL - 1u)

typedef _Float16 half2v  __attribute__((ext_vector_type(2)));
typedef _Float16 half4   __attribute__((ext_vector_type(4)));
typedef _Float16 half8   __attribute__((ext_vector_type(8)));
typedef float    floatx4 __attribute__((ext_vector_type(4)));
typedef unsigned int uint2v __attribute__((ext_vector_type(2)));
typedef unsigned int uint4v __attribute__((ext_vector_type(4)));

struct ResParams { float resf[NLEV]; };

__device__ __forceinline__ float sigmoidf(float x) {
    return 1.0f / (1.0f + __expf(-x));
}

__device__ __forceinline__ float2 unpack_h2(unsigned u) {
    union { unsigned u; half2v h; } c; c.u = u;
    return make_float2((float)c.h[0], (float)c.h[1]);
}

// XOR-swizzle for [*][64] f16 buffers: 16B col-blocks permuted by row&7.
__device__ __forceinline__ int swz64(int row, int col) {
    return row * 64 + ((((col >> 3) ^ (row & 7)) << 3) | (col & 7));
}
__device__ __forceinline__ int swz64_blk(int row, int blk) {
    return row * 64 + ((blk ^ (row & 7)) << 3);
}
__device__ __forceinline__ int swz16(int row, int col) {
    return row * 64 + ((((col >> 3) ^ (row & 7)) << 3) | (col & 7));
}
__device__ __forceinline__ int swz16_blk(int row, int blk) {
    return row * 64 + ((blk ^ (row & 7)) << 3);
}

// ---------------------------------------------------------------------------
// Kernel 0: tables f32 -> f16.
// ---------------------------------------------------------------------------
__global__ __launch_bounds__(256) void k_cvt(
    const float* __restrict__ src, _Float16* __restrict__ dst, int n4)
{
    const int i = blockIdx.x * 256 + threadIdx.x;
    if (i >= n4) return;
    const float4 v = ((const float4*)src)[i];
    half4 o; o[0] = (_Float16)v.x; o[1] = (_Float16)v.y;
    o[2] = (_Float16)v.z; o[3] = (_Float16)v.w;
    ((half4*)dst)[i] = o;
}

// ---------------------------------------------------------------------------
// Kernel 1: hash encoding, 1 sample/thread + x-pair 8B loads, VGPR capped at
// 128 (launch_bounds 256,4) so the gather latency is hidden by occupancy
// instead of per-thread software pipelining (round-7: VGPR 236, 11% occ).
// ---------------------------------------------------------------------------
struct SampPos { float x0, x1, x2; };

__device__ __forceinline__ SampPos load_pos(
    int i, const float* __restrict__ t_starts, const float* __restrict__ t_ends,
    const float* __restrict__ rays_o, const float* __restrict__ rays_d,
    const int* __restrict__ ray_indices,
    float a0, float a1, float a2, float ib0, float ib1, float ib2)
{
    const int   ri = ray_indices[i];
    const float tmid = 0.5f * (t_starts[i] + t_ends[i]);
    const float xn0 = (rays_o[ri*3+0] + rays_d[ri*3+0]*tmid - a0) * ib0;
    const float xn1 = (rays_o[ri*3+1] + rays_d[ri*3+1]*tmid - a1) * ib1;
    const float xn2 = (rays_o[ri*3+2] + rays_d[ri*3+2]*tmid - a2) * ib2;
    SampPos p;
    p.x0 = fminf(fmaxf(xn0, 0.f), 1.f);
    p.x1 = fminf(fmaxf(xn1, 0.f), 1.f);
    p.x2 = fminf(fmaxf(xn2, 0.f), 1.f);
    return p;
}

__global__ __launch_bounds__(256, 4) void k_hash1(
    const float* __restrict__ t_starts, const float* __restrict__ t_ends,
    const float* __restrict__ rays_o,   const float* __restrict__ rays_d,
    const int*   __restrict__ ray_indices,
    const _Float16* __restrict__ tabh,
    const float* __restrict__ aabb,
    _Float16* __restrict__ encG, int n, ResParams rp)
{
    const int i = blockIdx.x * 256 + threadIdx.x;
    if (i >= n) return;

    const float a0 = aabb[0], a1 = aabb[1], a2 = aabb[2];
    const float ib0 = 1.f / (aabb[3] - a0 + 1e-5f);
    const float ib1 = 1.f / (aabb[4] - a1 + 1e-5f);
    const float ib2 = 1.f / (aabb[5] - a2 + 1e-5f);

    const SampPos A = load_pos(i, t_starts, t_ends, rays_o, rays_d, ray_indices,
                               a0, a1, a2, ib0, ib1, ib2);

    union { _Float16 h[32]; uint4v q[4]; } ev;

    #pragma unroll
    for (int l = 0; l < NLEV; ++l) {
        const float resf = rp.resf[l];
        const _Float16* __restrict__ tab = tabh + (size_t)l * (size_t)(TBL * 2u);

        const float p0 = A.x0*resf, p1 = A.x1*resf, p2 = A.x2*resf;
        const float fl0 = floorf(p0), fl1 = floorf(p1), fl2 = floorf(p2);
        const float f0 = p0-fl0, f1 = p1-fl1, f2 = p2-fl2;
        const unsigned i0 = (unsigned)fl0, i1 = (unsigned)fl1, i2 = (unsigned)fl2;
        const unsigned hy0 = i1 * 2654435761u, hy1 = hy0 + 2654435761u;
        const unsigned hz0 = i2 * 805459861u,  hz1 = hz0 + 805459861u;
        const float g0 = 1.f-f0, g1 = 1.f-f1, g2 = 1.f-f2;
        const unsigned ryz[4] = { hy0^hz0, hy0^hz1, hy1^hz0, hy1^hz1 };
        const float    wyz[4] = { g1*g2,   g1*f2,   f1*g2,   f1*f2 };

        unsigned v0[4], v1[4];
        if (!(i0 & 1u)) {        // even: pair {h, h^1} in one aligned 8B load
            #pragma unroll
            for (int c = 0; c < 4; ++c) {
                const unsigned lo = (i0 ^ ryz[c]) & TMASK;
                const uint2v p = *(const uint2v*)(tab + (size_t)(lo & ~1u) * 2u);
                const unsigned sw = lo & 1u;
                v0[c] = sw ? p.y : p.x;
                v1[c] = sw ? p.x : p.y;
            }
        } else {                 // odd: two independent 4B loads
            #pragma unroll
            for (int c = 0; c < 4; ++c) {
                const unsigned lo = (i0        ^ ryz[c]) & TMASK;
                const unsigned hi = ((i0 + 1u) ^ ryz[c]) & TMASK;
                v0[c] = *(const unsigned*)(tab + (size_t)lo * 2u);
                v1[c] = *(const unsigned*)(tab + (size_t)hi * 2u);
            }
        }

        float e0 = 0.f, e1 = 0.f;
        #pragma unroll
        for (int c = 0; c < 4; ++c) {
            const float wlo = g0 * wyz[c], whi = f0 * wyz[c];
            const float2 t0 = unpack_h2(v0[c]), t1 = unpack_h2(v1[c]);
            e0 += wlo * t0.x + whi * t1.x;
            e1 += wlo * t0.y + whi * t1.y;
        }
        ev.h[2*l]   = (_Float16)(e0 * 1024.f);   // *1024: f16-normal range
        ev.h[2*l+1] = (_Float16)(e1 * 1024.f);
    }

    uint4v* dst = (uint4v*)(encG + (size_t)i * 32);
    #pragma unroll
    for (int q = 0; q < 4; ++q) __builtin_nontemporal_store(ev.q[q], dst + q);
}

// ---------------------------------------------------------------------------
// Kernel 2: fused MLP, all five layers via MFMA (unchanged from round 7).
// ---------------------------------------------------------------------------
__global__ __launch_bounds__(256) void k_mlp(
    const float* __restrict__ t_starts, const float* __restrict__ t_ends,
    const float* __restrict__ rays_o,   const float* __restrict__ rays_d,
    const int*   __restrict__ ray_indices,
    const float* __restrict__ bw0,  // [32,64]
    const float* __restrict__ bw1,  // [64,16]
    const float* __restrict__ hw0,  // [31,64]
    const float* __restrict__ hw1,  // [64,64]
    const float* __restrict__ hw2,  // [64,3]
    const float* __restrict__ aabb,
    const _Float16* __restrict__ encG,
    float4* __restrict__ srgb, int n)
{
    __shared__ _Float16 sT  [4][16 * 72];
    __shared__ _Float16 sSH [256 * 16];
    __shared__ _Float16 sHB [256 * 16];
    __shared__ _Float16 sW0T[64 * 40];
    __shared__ _Float16 sW1T[64 * 64];
    __shared__ _Float16 sBW0T[64 * 32];
    __shared__ _Float16 sBW1T[16 * 64];
    __shared__ float    sDT [256];

    const int t     = threadIdx.x;
    const int gbase = blockIdx.x * 256;

    {
        const int s  = gbase + t;            // n % 256 == 0
        const int ri = ray_indices[s];
        const float ts = t_starts[s], te = t_ends[s];
        const float tmid = 0.5f * (ts + te);
        const float ox = rays_o[ri*3+0], oy = rays_o[ri*3+1], oz = rays_o[ri*3+2];
        const float dx = rays_d[ri*3+0], dy = rays_d[ri*3+1], dz = rays_d[ri*3+2];
        const float a0 = aabb[0], a1 = aabb[1], a2c = aabb[2];
        const float b0 = aabb[3], b1 = aabb[4], b2c = aabb[5];
        const float xn0 = (ox + dx*tmid - a0) / (b0 - a0 + 1e-5f);
        const float xn1 = (oy + dy*tmid - a1) / (b1 - a1 + 1e-5f);
        const float xn2 = (oz + dz*tmid - a2c) / (b2c - a2c + 1e-5f);
        const bool sel = (xn0 > 0.f) && (xn0 < 1.f) && (xn1 > 0.f) && (xn1 < 1.f)
                      && (xn2 > 0.f) && (xn2 < 1.f);
        sDT[t] = sel ? (te - ts) : 0.f;

        const float x = dx, y = dy, z = dz;
        const float x2 = x*x, y2 = y*y, z2 = z*z;
        const float xy = x*y, yz = y*z, xz = x*z;
        float shv[16];
        shv[0]  = 0.28209479177387814f;
        shv[1]  = -0.48860251190291987f * y;
        shv[2]  = 0.48860251190291987f * z;
        shv[3]  = -0.48860251190291987f * x;
        shv[4]  = 1.0925484305920792f * xy;
        shv[5]  = -1.0925484305920792f * yz;
        shv[6]  = 0.94617469575756f * z2 - 0.31539156525252005f;
        shv[7]  = -1.0925484305920792f * xz;
        shv[8]  = 0.5462742152960396f * (x2 - y2);
        shv[9]  = -0.5900435899266435f * y * (3.f*x2 - y2);
        shv[10] = 2.890611442640554f * xy * z;
        shv[11] = -0.4570457994644658f * y * (4.f*z2 - x2 - y2);
        shv[12] = 0.3731763325901154f * z * (2.f*z2 - 3.f*x2 - 3.f*y2);
        shv[13] = -0.4570457994644658f * x * (4.f*z2 - x2 - y2);
        shv[14] = 1.445305721320277f * z * (x2 - y2);
        shv[15] = -0.5900435899266435f * x * (x2 - 3.f*y2);
        #pragma unroll
        for (int k4 = 0; k4 < 4; ++k4) {
            half4 p;
            #pragma unroll
            for (int j = 0; j < 4; ++j) p[j] = (_Float16)shv[k4*4 + j];
            *(half4*)&sSH[t*16 + k4*4] = p;
        }
    }
    {
        const int nidx = t & 63, g = t >> 6;
        #pragma unroll
        for (int i2 = 0; i2 < 8; ++i2) {
            const int k = g*8 + i2;
            const float v = (k < 31) ? hw0[k*64 + nidx] : 0.f;
            sW0T[nidx*40 + k] = (_Float16)v;
        }
        #pragma unroll
        for (int i2 = 0; i2 < 16; ++i2) {
            const int k = g*16 + i2;
            sW1T[swz64(nidx, k)] = (_Float16)hw1[k*64 + nidx];
        }
        #pragma unroll
        for (int i2 = 0; i2 < 8; ++i2) {
            const int k = g*8 + i2;
            sBW0T[nidx*32 + k] = (_Float16)bw0[k*64 + nidx];
        }
    }
    {
        const int nidx = t & 15, g = t >> 4;
        #pragma unroll
        for (int i2 = 0; i2 < 4; ++i2) {
            const int k = g*4 + i2;
            sBW1T[swz16(nidx, k)] = (_Float16)bw1[k*16 + nidx];
        }
    }

    const int lane = t & 63, w = t >> 6;
    const int nn = lane & 15, quad = lane >> 4;
    _Float16* myT = &sT[w][0];

    half8 BH2[2];
    #pragma unroll
    for (int ks = 0; ks < 2; ++ks)
        #pragma unroll
        for (int j = 0; j < 8; ++j) {
            const int k = ks*32 + quad*8 + j;
            BH2[ks][j] = (nn < 3) ? (_Float16)hw2[k*3 + nn] : (_Float16)0.f;
        }

    __syncthreads();

    const int rbase = w * 64;

    #pragma unroll
    for (int rt = 0; rt < 4; ++rt) {
        const int srow = rbase + rt*16;
        const int drow = srow + quad*4;

        // ---- GEMM1 (transposed): hid^T = bw0^T @ enc^T ----
        half8 bE = *(const half8*)(encG + (size_t)(gbase + srow + nn)*32 + quad*8);
        #pragma unroll
        for (int ct = 0; ct < 4; ++ct) {
            half8 aW = *(const half8*)&sBW0T[(ct*16 + nn)*32 + quad*8];
            floatx4 acc = {0.f, 0.f, 0.f, 0.f};
            acc = __builtin_amdgcn_mfma_f32_16x16x32_f16(aW, bE, acc, 0, 0, 0);
            half4 p;
            #pragma unroll
            for (int r2 = 0; r2 < 4; ++r2) p[r2] = (_Float16)fmaxf(acc[r2], 0.f);
            *(half4*)&myT[nn*72 + ct*16 + quad*4] = p;
        }

        // ---- GEMM2: h = hid @ bw1; sigma broadcast ----
        float sigr[4];
        {
            half8 a20 = *(const half8*)&myT[nn*72 +  0 + quad*8];
            half8 a21 = *(const half8*)&myT[nn*72 + 32 + quad*8];
            half8 b20 = *(const half8*)&sBW1T[swz16_blk(nn, quad)];
            half8 b21 = *(const half8*)&sBW1T[swz16_blk(nn, 4 + quad)];
            floatx4 acc = {0.f, 0.f, 0.f, 0.f};
            acc = __builtin_amdgcn_mfma_f32_16x16x32_f16(a20, b20, acc, 0, 0, 0);
            acc = __builtin_amdgcn_mfma_f32_16x16x32_f16(a21, b21, acc, 0, 0, 0);
            #pragma unroll
            for (int r2 = 0; r2 < 4; ++r2) {
                const float h = acc[r2] * (1.f / 1024.f);
                const float h0 = __shfl(h, lane & 0x30, 64);
                sigr[r2] = __expf(h0 - 1.f) * sDT[drow + r2];
                if (nn == 0) sHB[(drow + r2)*16 + 15] = (_Float16)0.f;
                else         sHB[(drow + r2)*16 + (nn - 1)] = (_Float16)h;
            }
        }

        // ---- GEMM3 (transposed): a2^T = hw0^T @ hh^T ----
        half8 shf = *(const half8*)&sSH[(srow + nn)*16 + (quad & 1)*8];
        half8 hbf = *(const half8*)&sHB[(srow + nn)*16 + (quad & 1)*8];
        half8 a3f = (quad < 2) ? shf : hbf;
        #pragma unroll
        for (int ct = 0; ct < 4; ++ct) {
            half8 aW = *(const half8*)&sW0T[(ct*16 + nn)*40 + quad*8];
            floatx4 acc = {0.f, 0.f, 0.f, 0.f};
            acc = __builtin_amdgcn_mfma_f32_16x16x32_f16(aW, a3f, acc, 0, 0, 0);
            half4 p;
            #pragma unroll
            for (int r2 = 0; r2 < 4; ++r2) p[r2] = (_Float16)fmaxf(acc[r2], 0.f);
            *(half4*)&myT[nn*72 + ct*16 + quad*4] = p;
        }

        // ---- GEMM4 (transposed): a3^T = hw1^T @ a2^T ----
        half8 af0 = *(const half8*)&myT[nn*72 +  0 + quad*8];
        half8 af1 = *(const half8*)&myT[nn*72 + 32 + quad*8];
        #pragma unroll
        for (int ct = 0; ct < 4; ++ct) {
            half8 aW0 = *(const half8*)&sW1T[swz64_blk(ct*16 + nn, quad)];
            half8 aW1 = *(const half8*)&sW1T[swz64_blk(ct*16 + nn, 4 + quad)];
            floatx4 acc = {0.f, 0.f, 0.f, 0.f};
            acc = __builtin_amdgcn_mfma_f32_16x16x32_f16(aW0, af0, acc, 0, 0, 0);
            acc = __builtin_amdgcn_mfma_f32_16x16x32_f16(aW1, af1, acc, 0, 0, 0);
            half4 p;
            #pragma unroll
            for (int r2 = 0; r2 < 4; ++r2) p[r2] = (_Float16)fmaxf(acc[r2], 0.f);
            *(half4*)&myT[nn*72 + ct*16 + quad*4] = p;
        }

        // ---- GEMM5: rgb = a3 @ hw2 ----
        {
            half8 a50 = *(const half8*)&myT[nn*72 +  0 + quad*8];
            half8 a51 = *(const half8*)&myT[nn*72 + 32 + quad*8];
            floatx4 acc = {0.f, 0.f, 0.f, 0.f};
            acc = __builtin_amdgcn_mfma_f32_16x16x32_f16(a50, BH2[0], acc, 0, 0, 0);
            acc = __builtin_amdgcn_mfma_f32_16x16x32_f16(a51, BH2[1], acc, 0, 0, 0);
            #pragma unroll
            for (int r2 = 0; r2 < 4; ++r2) {
                float* bp = (float*)&srgb[gbase + drow + r2];
                if (nn < 3)       bp[1 + nn] = sigmoidf(acc[r2]);
                else if (nn == 3) bp[0]      = sigr[r2];
            }
        }
    }
}

// ---------------------------------------------------------------------------
// Kernel 3: wave-per-ray compositing with shfl prefix scan (unchanged).
// ---------------------------------------------------------------------------
__global__ __launch_bounds__(256) void k_render(
    const float* __restrict__ t_starts, const float* __restrict__ t_ends,
    const int*   __restrict__ ray_indices,
    const float4* __restrict__ srgb,
    float* __restrict__ out, int n_samples, int n_rays)
{
    const int wid  = (blockIdx.x * 256 + threadIdx.x) >> 6;
    const int lane = threadIdx.x & 63;
    if (wid >= n_rays) return;
    const int r = wid;

    int lo = 0, hi = n_samples;
    while (lo < hi) { int mid = (lo + hi) >> 1; if (ray_indices[mid] <  r) lo = mid + 1; else hi = mid; }
    const int start = lo;
    hi = n_samples;
    while (lo < hi) { int mid = (lo + hi) >> 1; if (ray_indices[mid] <= r) lo = mid + 1; else hi = mid; }
    const int end = lo;

    float S = 0.f, cr = 0.f, cg = 0.f, cb = 0.f, op = 0.f, dw = 0.f;
    for (int j0 = start; j0 < end; j0 += 64) {
        const int j = j0 + lane;
        float s = 0.f, R = 0.f, G = 0.f, B = 0.f, tm = 0.f;
        if (j < end) {
            const float4 v = srgb[j];
            s = v.x; R = v.y; G = v.z; B = v.w;
            tm = 0.5f * (t_starts[j] + t_ends[j]);
        }
        float incl = s;
        #pragma unroll
        for (int off = 1; off < 64; off <<= 1) {
            const float tv = __shfl_up(incl, off, 64);
            if (lane >= off) incl += tv;
        }
        const float excl  = incl - s;
        const float trans = __expf(-(S + excl));
        const float alpha = 1.f - __expf(-s);
        const float wgt   = trans * alpha;
        cr += wgt * R; cg += wgt * G; cb += wgt * B;
        op += wgt;     dw += wgt * tm;
        S += __shfl(incl, 63, 64);
    }
    #pragma unroll
    for (int off = 1; off < 64; off <<= 1) {
        cr += __shfl_xor(cr, off, 64);
        cg += __shfl_xor(cg, off, 64);
        cb += __shfl_xor(cb, off, 64);
        op += __shfl_xor(op, off, 64);
        dw += __shfl_xor(dw, off, 64);
    }
    if (lane == 0) {
        out[r*3 + 0] = cr;
        out[r*3 + 1] = cg;
        out[r*3 + 2] = cb;
        out[n_rays*3 + r] = op;
        out[n_rays*4 + r] = dw / fmaxf(op, 1.1920929e-7f);
    }
}

// ---------------------------------------------------------------------------
extern "C" void kernel_launch(void* const* d_in, const int* in_sizes, int n_in,
                              void* d_out, int out_size, void* d_ws, size_t ws_size,
                              hipStream_t stream)
{
    const float* t_starts    = (const float*)d_in[0];
    const float* t_ends      = (const float*)d_in[1];
    const float* rays_o      = (const float*)d_in[2];
    const float* rays_d      = (const float*)d_in[3];
    const int*   ray_indices = (const int*)  d_in[4];
    const float* tables      = (const float*)d_in[5];
    const float* bw0         = (const float*)d_in[6];
    const float* bw1         = (const float*)d_in[7];
    const float* hw0         = (const float*)d_in[8];
    const float* hw1         = (const float*)d_in[9];
    const float* hw2         = (const float*)d_in[10];
    const float* aabb        = (const float*)d_in[11];

    const int n      = in_sizes[0];        // 524288
    const int n_rays = in_sizes[2] / 3;    // 8192
    const int tbl_n  = in_sizes[5];        // 16*T*2 floats

    float* out = (float*)d_out;
    char*  ws  = (char*)d_ws;

    const size_t tabh_bytes = (size_t)tbl_n * 2;
    const size_t enc_bytes  = (size_t)n * 64;

    ResParams rp;
    const double scale = exp((log(4096.0) - log(16.0)) / 15.0);
    for (int l = 0; l < NLEV; ++l)
        rp.resf[l] = (float)floor(16.0 * pow(scale, (double)l));

    _Float16* tabh = (_Float16*)ws;
    _Float16* encG = (_Float16*)(ws + tabh_bytes);
    float4*   srgb = (float4*)(ws + tabh_bytes + enc_bytes);

    const int n4 = tbl_n / 4;
    k_cvt<<<(n4 + 255)/256, 256, 0, stream>>>(tables, tabh, n4);

    k_hash1<<<(n + 255)/256, 256, 0, stream>>>(
        t_starts, t_ends, rays_o, rays_d, ray_indices, tabh, aabb, encG, n, rp);

    k_mlp<<<(n + 255)/256, 256, 0, stream>>>(
        t_starts, t_ends, rays_o, rays_d, ray_indices, bw0, bw1, hw0, hw1, hw2,
        aabb, encG, srgb, n);
    k_render<<<(n_rays*64 + 255)/256, 256, 0, stream>>>(
        t_starts, t_ends, ray_indices, srgb, out, n, n_rays);
}

// Round 9
// 321.961 us; speedup vs baseline: 1.3874x; 1.3874x over previous
//
#include <hip/hip_runtime.h>
#include <math.h>

#define NLEV 16
#define TBL  (1u << 19)
#define TMASK (TBL - 1u)

typedef _Float16 half2v  __attribute__((ext_vector_type(2)));
typedef _Float16 half4   __attribute__((ext_vector_type(4)));
typedef _Float16 half8   __attribute__((ext_vector_type(8)));
typedef float    floatx4 __attribute__((ext_vector_type(4)));
typedef unsigned int uint2v __attribute__((ext_vector_type(2)));
typedef unsigned int uint4v __attribute__((ext_vector_type(4)));

struct ResParams { float resf[NLEV]; };

__device__ __forceinline__ float sigmoidf(float x) {
    return 1.0f / (1.0f + __expf(-x));
}

__device__ __forceinline__ float2 unpack_h2(unsigned u) {
    union { unsigned u; half2v h; } c; c.u = u;
    return make_float2((float)c.h[0], (float)c.h[1]);
}

// XOR-swizzle for [*][64] f16 buffers: 16B col-blocks permuted by row&7.
__device__ __forceinline__ int swz64(int row, int col) {
    return row * 64 + ((((col >> 3) ^ (row & 7)) << 3) | (col & 7));
}
__device__ __forceinline__ int swz64_blk(int row, int blk) {
    return row * 64 + ((blk ^ (row & 7)) << 3);
}
__device__ __forceinline__ int swz16(int row, int col) {
    return row * 64 + ((((col >> 3) ^ (row & 7)) << 3) | (col & 7));
}
__device__ __forceinline__ int swz16_blk(int row, int blk) {
    return row * 64 + ((blk ^ (row & 7)) << 3);
}

// ---------------------------------------------------------------------------
// Kernel 0: tables f32 -> f16.
// ---------------------------------------------------------------------------
__global__ __launch_bounds__(256) void k_cvt(
    const float* __restrict__ src, _Float16* __restrict__ dst, int n4)
{
    const int i = blockIdx.x * 256 + threadIdx.x;
    if (i >= n4) return;
    const float4 v = ((const float4*)src)[i];
    half4 o; o[0] = (_Float16)v.x; o[1] = (_Float16)v.y;
    o[2] = (_Float16)v.z; o[3] = (_Float16)v.w;
    ((half4*)dst)[i] = o;
}

// ---------------------------------------------------------------------------
// Kernel 1: hash encoding, 1 sample/thread, x-pair 8B loads, NO VGPR cap.
// (Round 8's launch_bounds(256,4) cap caused 64-VGPR + ~300MB scratch spill;
// round 7's 2-sample version needed 236 VGPR. This is the untried cell:
// natural demand ~half of 2-sample -> ~4 waves/SIMD without spilling.)
// ---------------------------------------------------------------------------
struct SampPos { float x0, x1, x2; };

__device__ __forceinline__ SampPos load_pos(
    int i, const float* __restrict__ t_starts, const float* __restrict__ t_ends,
    const float* __restrict__ rays_o, const float* __restrict__ rays_d,
    const int* __restrict__ ray_indices,
    float a0, float a1, float a2, float ib0, float ib1, float ib2)
{
    const int   ri = ray_indices[i];
    const float tmid = 0.5f * (t_starts[i] + t_ends[i]);
    const float xn0 = (rays_o[ri*3+0] + rays_d[ri*3+0]*tmid - a0) * ib0;
    const float xn1 = (rays_o[ri*3+1] + rays_d[ri*3+1]*tmid - a1) * ib1;
    const float xn2 = (rays_o[ri*3+2] + rays_d[ri*3+2]*tmid - a2) * ib2;
    SampPos p;
    p.x0 = fminf(fmaxf(xn0, 0.f), 1.f);
    p.x1 = fminf(fmaxf(xn1, 0.f), 1.f);
    p.x2 = fminf(fmaxf(xn2, 0.f), 1.f);
    return p;
}

__global__ __launch_bounds__(256) void k_hash1(
    const float* __restrict__ t_starts, const float* __restrict__ t_ends,
    const float* __restrict__ rays_o,   const float* __restrict__ rays_d,
    const int*   __restrict__ ray_indices,
    const _Float16* __restrict__ tabh,
    const float* __restrict__ aabb,
    _Float16* __restrict__ encG, int n, ResParams rp)
{
    const int i = blockIdx.x * 256 + threadIdx.x;
    if (i >= n) return;

    const float a0 = aabb[0], a1 = aabb[1], a2 = aabb[2];
    const float ib0 = 1.f / (aabb[3] - a0 + 1e-5f);
    const float ib1 = 1.f / (aabb[4] - a1 + 1e-5f);
    const float ib2 = 1.f / (aabb[5] - a2 + 1e-5f);

    const SampPos A = load_pos(i, t_starts, t_ends, rays_o, rays_d, ray_indices,
                               a0, a1, a2, ib0, ib1, ib2);

    union { _Float16 h[32]; uint4v q[4]; } ev;

    #pragma unroll
    for (int l = 0; l < NLEV; ++l) {
        const float resf = rp.resf[l];
        const _Float16* __restrict__ tab = tabh + (size_t)l * (size_t)(TBL * 2u);

        const float p0 = A.x0*resf, p1 = A.x1*resf, p2 = A.x2*resf;
        const float fl0 = floorf(p0), fl1 = floorf(p1), fl2 = floorf(p2);
        const float f0 = p0-fl0, f1 = p1-fl1, f2 = p2-fl2;
        const unsigned i0 = (unsigned)fl0, i1 = (unsigned)fl1, i2 = (unsigned)fl2;
        const unsigned hy0 = i1 * 2654435761u, hy1 = hy0 + 2654435761u;
        const unsigned hz0 = i2 * 805459861u,  hz1 = hz0 + 805459861u;
        const float g0 = 1.f-f0, g1 = 1.f-f1, g2 = 1.f-f2;
        const unsigned ryz[4] = { hy0^hz0, hy0^hz1, hy1^hz0, hy1^hz1 };
        const float    wyz[4] = { g1*g2,   g1*f2,   f1*g2,   f1*f2 };

        unsigned v0[4], v1[4];
        if (!(i0 & 1u)) {        // even: pair {h, h^1} in one aligned 8B load
            #pragma unroll
            for (int c = 0; c < 4; ++c) {
                const unsigned lo = (i0 ^ ryz[c]) & TMASK;
                const uint2v p = *(const uint2v*)(tab + (size_t)(lo & ~1u) * 2u);
                const unsigned sw = lo & 1u;
                v0[c] = sw ? p.y : p.x;
                v1[c] = sw ? p.x : p.y;
            }
        } else {                 // odd: two independent 4B loads
            #pragma unroll
            for (int c = 0; c < 4; ++c) {
                const unsigned lo = (i0        ^ ryz[c]) & TMASK;
                const unsigned hi = ((i0 + 1u) ^ ryz[c]) & TMASK;
                v0[c] = *(const unsigned*)(tab + (size_t)lo * 2u);
                v1[c] = *(const unsigned*)(tab + (size_t)hi * 2u);
            }
        }

        float e0 = 0.f, e1 = 0.f;
        #pragma unroll
        for (int c = 0; c < 4; ++c) {
            const float wlo = g0 * wyz[c], whi = f0 * wyz[c];
            const float2 t0 = unpack_h2(v0[c]), t1 = unpack_h2(v1[c]);
            e0 += wlo * t0.x + whi * t1.x;
            e1 += wlo * t0.y + whi * t1.y;
        }
        ev.h[2*l]   = (_Float16)(e0 * 1024.f);   // *1024: f16-normal range
        ev.h[2*l+1] = (_Float16)(e1 * 1024.f);
    }

    uint4v* dst = (uint4v*)(encG + (size_t)i * 32);
    #pragma unroll
    for (int q = 0; q < 4; ++q) __builtin_nontemporal_store(ev.q[q], dst + q);
}

// ---------------------------------------------------------------------------
// Kernel 2: fused MLP, all five layers via MFMA (round-7 version).
// ---------------------------------------------------------------------------
__global__ __launch_bounds__(256) void k_mlp(
    const float* __restrict__ t_starts, const float* __restrict__ t_ends,
    const float* __restrict__ rays_o,   const float* __restrict__ rays_d,
    const int*   __restrict__ ray_indices,
    const float* __restrict__ bw0,  // [32,64]
    const float* __restrict__ bw1,  // [64,16]
    const float* __restrict__ hw0,  // [31,64]
    const float* __restrict__ hw1,  // [64,64]
    const float* __restrict__ hw2,  // [64,3]
    const float* __restrict__ aabb,
    const _Float16* __restrict__ encG,
    float4* __restrict__ srgb, int n)
{
    __shared__ _Float16 sT  [4][16 * 72];
    __shared__ _Float16 sSH [256 * 16];
    __shared__ _Float16 sHB [256 * 16];
    __shared__ _Float16 sW0T[64 * 40];
    __shared__ _Float16 sW1T[64 * 64];
    __shared__ _Float16 sBW0T[64 * 32];
    __shared__ _Float16 sBW1T[16 * 64];
    __shared__ float    sDT [256];

    const int t     = threadIdx.x;
    const int gbase = blockIdx.x * 256;

    {
        const int s  = gbase + t;            // n % 256 == 0
        const int ri = ray_indices[s];
        const float ts = t_starts[s], te = t_ends[s];
        const float tmid = 0.5f * (ts + te);
        const float ox = rays_o[ri*3+0], oy = rays_o[ri*3+1], oz = rays_o[ri*3+2];
        const float dx = rays_d[ri*3+0], dy = rays_d[ri*3+1], dz = rays_d[ri*3+2];
        const float a0 = aabb[0], a1 = aabb[1], a2c = aabb[2];
        const float b0 = aabb[3], b1 = aabb[4], b2c = aabb[5];
        const float xn0 = (ox + dx*tmid - a0) / (b0 - a0 + 1e-5f);
        const float xn1 = (oy + dy*tmid - a1) / (b1 - a1 + 1e-5f);
        const float xn2 = (oz + dz*tmid - a2c) / (b2c - a2c + 1e-5f);
        const bool sel = (xn0 > 0.f) && (xn0 < 1.f) && (xn1 > 0.f) && (xn1 < 1.f)
                      && (xn2 > 0.f) && (xn2 < 1.f);
        sDT[t] = sel ? (te - ts) : 0.f;

        const float x = dx, y = dy, z = dz;
        const float x2 = x*x, y2 = y*y, z2 = z*z;
        const float xy = x*y, yz = y*z, xz = x*z;
        float shv[16];
        shv[0]  = 0.28209479177387814f;
        shv[1]  = -0.48860251190291987f * y;
        shv[2]  = 0.48860251190291987f * z;
        shv[3]  = -0.48860251190291987f * x;
        shv[4]  = 1.0925484305920792f * xy;
        shv[5]  = -1.0925484305920792f * yz;
        shv[6]  = 0.94617469575756f * z2 - 0.31539156525252005f;
        shv[7]  = -1.0925484305920792f * xz;
        shv[8]  = 0.5462742152960396f * (x2 - y2);
        shv[9]  = -0.5900435899266435f * y * (3.f*x2 - y2);
        shv[10] = 2.890611442640554f * xy * z;
        shv[11] = -0.4570457994644658f * y * (4.f*z2 - x2 - y2);
        shv[12] = 0.3731763325901154f * z * (2.f*z2 - 3.f*x2 - 3.f*y2);
        shv[13] = -0.4570457994644658f * x * (4.f*z2 - x2 - y2);
        shv[14] = 1.445305721320277f * z * (x2 - y2);
        shv[15] = -0.5900435899266435f * x * (x2 - 3.f*y2);
        #pragma unroll
        for (int k4 = 0; k4 < 4; ++k4) {
            half4 p;
            #pragma unroll
            for (int j = 0; j < 4; ++j) p[j] = (_Float16)shv[k4*4 + j];
            *(half4*)&sSH[t*16 + k4*4] = p;
        }
    }
    {
        const int nidx = t & 63, g = t >> 6;
        #pragma unroll
        for (int i2 = 0; i2 < 8; ++i2) {
            const int k = g*8 + i2;
            const float v = (k < 31) ? hw0[k*64 + nidx] : 0.f;
            sW0T[nidx*40 + k] = (_Float16)v;
        }
        #pragma unroll
        for (int i2 = 0; i2 < 16; ++i2) {
            const int k = g*16 + i2;
            sW1T[swz64(nidx, k)] = (_Float16)hw1[k*64 + nidx];
        }
        #pragma unroll
        for (int i2 = 0; i2 < 8; ++i2) {
            const int k = g*8 + i2;
            sBW0T[nidx*32 + k] = (_Float16)bw0[k*64 + nidx];
        }
    }
    {
        const int nidx = t & 15, g = t >> 4;
        #pragma unroll
        for (int i2 = 0; i2 < 4; ++i2) {
            const int k = g*4 + i2;
            sBW1T[swz16(nidx, k)] = (_Float16)bw1[k*16 + nidx];
        }
    }

    const int lane = t & 63, w = t >> 6;
    const int nn = lane & 15, quad = lane >> 4;
    _Float16* myT = &sT[w][0];

    half8 BH2[2];
    #pragma unroll
    for (int ks = 0; ks < 2; ++ks)
        #pragma unroll
        for (int j = 0; j < 8; ++j) {
            const int k = ks*32 + quad*8 + j;
            BH2[ks][j] = (nn < 3) ? (_Float16)hw2[k*3 + nn] : (_Float16)0.f;
        }

    __syncthreads();

    const int rbase = w * 64;

    #pragma unroll
    for (int rt = 0; rt < 4; ++rt) {
        const int srow = rbase + rt*16;
        const int drow = srow + quad*4;

        // ---- GEMM1 (transposed): hid^T = bw0^T @ enc^T ----
        half8 bE = *(const half8*)(encG + (size_t)(gbase + srow + nn)*32 + quad*8);
        #pragma unroll
        for (int ct = 0; ct < 4; ++ct) {
            half8 aW = *(const half8*)&sBW0T[(ct*16 + nn)*32 + quad*8];
            floatx4 acc = {0.f, 0.f, 0.f, 0.f};
            acc = __builtin_amdgcn_mfma_f32_16x16x32_f16(aW, bE, acc, 0, 0, 0);
            half4 p;
            #pragma unroll
            for (int r2 = 0; r2 < 4; ++r2) p[r2] = (_Float16)fmaxf(acc[r2], 0.f);
            *(half4*)&myT[nn*72 + ct*16 + quad*4] = p;
        }

        // ---- GEMM2: h = hid @ bw1; sigma broadcast ----
        float sigr[4];
        {
            half8 a20 = *(const half8*)&myT[nn*72 +  0 + quad*8];
            half8 a21 = *(const half8*)&myT[nn*72 + 32 + quad*8];
            half8 b20 = *(const half8*)&sBW1T[swz16_blk(nn, quad)];
            half8 b21 = *(const half8*)&sBW1T[swz16_blk(nn, 4 + quad)];
            floatx4 acc = {0.f, 0.f, 0.f, 0.f};
            acc = __builtin_amdgcn_mfma_f32_16x16x32_f16(a20, b20, acc, 0, 0, 0);
            acc = __builtin_amdgcn_mfma_f32_16x16x32_f16(a21, b21, acc, 0, 0, 0);
            #pragma unroll
            for (int r2 = 0; r2 < 4; ++r2) {
                const float h = acc[r2] * (1.f / 1024.f);
                const float h0 = __shfl(h, lane & 0x30, 64);
                sigr[r2] = __expf(h0 - 1.f) * sDT[drow + r2];
                if (nn == 0) sHB[(drow + r2)*16 + 15] = (_Float16)0.f;
                else         sHB[(drow + r2)*16 + (nn - 1)] = (_Float16)h;
            }
        }

        // ---- GEMM3 (transposed): a2^T = hw0^T @ hh^T ----
        half8 shf = *(const half8*)&sSH[(srow + nn)*16 + (quad & 1)*8];
        half8 hbf = *(const half8*)&sHB[(srow + nn)*16 + (quad & 1)*8];
        half8 a3f = (quad < 2) ? shf : hbf;
        #pragma unroll
        for (int ct = 0; ct < 4; ++ct) {
            half8 aW = *(const half8*)&sW0T[(ct*16 + nn)*40 + quad*8];
            floatx4 acc = {0.f, 0.f, 0.f, 0.f};
            acc = __builtin_amdgcn_mfma_f32_16x16x32_f16(aW, a3f, acc, 0, 0, 0);
            half4 p;
            #pragma unroll
            for (int r2 = 0; r2 < 4; ++r2) p[r2] = (_Float16)fmaxf(acc[r2], 0.f);
            *(half4*)&myT[nn*72 + ct*16 + quad*4] = p;
        }

        // ---- GEMM4 (transposed): a3^T = hw1^T @ a2^T ----
        half8 af0 = *(const half8*)&myT[nn*72 +  0 + quad*8];
        half8 af1 = *(const half8*)&myT[nn*72 + 32 + quad*8];
        #pragma unroll
        for (int ct = 0; ct < 4; ++ct) {
            half8 aW0 = *(const half8*)&sW1T[swz64_blk(ct*16 + nn, quad)];
            half8 aW1 = *(const half8*)&sW1T[swz64_blk(ct*16 + nn, 4 + quad)];
            floatx4 acc = {0.f, 0.f, 0.f, 0.f};
            acc = __builtin_amdgcn_mfma_f32_16x16x32_f16(aW0, af0, acc, 0, 0, 0);
            acc = __builtin_amdgcn_mfma_f32_16x16x32_f16(aW1, af1, acc, 0, 0, 0);
            half4 p;
            #pragma unroll
            for (int r2 = 0; r2 < 4; ++r2) p[r2] = (_Float16)fmaxf(acc[r2], 0.f);
            *(half4*)&myT[nn*72 + ct*16 + quad*4] = p;
        }

        // ---- GEMM5: rgb = a3 @ hw2 ----
        {
            half8 a50 = *(const half8*)&myT[nn*72 +  0 + quad*8];
            half8 a51 = *(const half8*)&myT[nn*72 + 32 + quad*8];
            floatx4 acc = {0.f, 0.f, 0.f, 0.f};
            acc = __builtin_amdgcn_mfma_f32_16x16x32_f16(a50, BH2[0], acc, 0, 0, 0);
            acc = __builtin_amdgcn_mfma_f32_16x16x32_f16(a51, BH2[1], acc, 0, 0, 0);
            #pragma unroll
            for (int r2 = 0; r2 < 4; ++r2) {
                float* bp = (float*)&srgb[gbase + drow + r2];
                if (nn < 3)       bp[1 + nn] = sigmoidf(acc[r2]);
                else if (nn == 3) bp[0]      = sigr[r2];
            }
        }
    }
}

// ---------------------------------------------------------------------------
// Kernel 3: wave-per-ray compositing with shfl prefix scan.
// ---------------------------------------------------------------------------
__global__ __launch_bounds__(256) void k_render(
    const float* __restrict__ t_starts, const float* __restrict__ t_ends,
    const int*   __restrict__ ray_indices,
    const float4* __restrict__ srgb,
    float* __restrict__ out, int n_samples, int n_rays)
{
    const int wid  = (blockIdx.x * 256 + threadIdx.x) >> 6;
    const int lane = threadIdx.x & 63;
    if (wid >= n_rays) return;
    const int r = wid;

    int lo = 0, hi = n_samples;
    while (lo < hi) { int mid = (lo + hi) >> 1; if (ray_indices[mid] <  r) lo = mid + 1; else hi = mid; }
    const int start = lo;
    hi = n_samples;
    while (lo < hi) { int mid = (lo + hi) >> 1; if (ray_indices[mid] <= r) lo = mid + 1; else hi = mid; }
    const int end = lo;

    float S = 0.f, cr = 0.f, cg = 0.f, cb = 0.f, op = 0.f, dw = 0.f;
    for (int j0 = start; j0 < end; j0 += 64) {
        const int j = j0 + lane;
        float s = 0.f, R = 0.f, G = 0.f, B = 0.f, tm = 0.f;
        if (j < end) {
            const float4 v = srgb[j];
            s = v.x; R = v.y; G = v.z; B = v.w;
            tm = 0.5f * (t_starts[j] + t_ends[j]);
        }
        float incl = s;
        #pragma unroll
        for (int off = 1; off < 64; off <<= 1) {
            const float tv = __shfl_up(incl, off, 64);
            if (lane >= off) incl += tv;
        }
        const float excl  = incl - s;
        const float trans = __expf(-(S + excl));
        const float alpha = 1.f - __expf(-s);
        const float wgt   = trans * alpha;
        cr += wgt * R; cg += wgt * G; cb += wgt * B;
        op += wgt;     dw += wgt * tm;
        S += __shfl(incl, 63, 64);
    }
    #pragma unroll
    for (int off = 1; off < 64; off <<= 1) {
        cr += __shfl_xor(cr, off, 64);
        cg += __shfl_xor(cg, off, 64);
        cb += __shfl_xor(cb, off, 64);
        op += __shfl_xor(op, off, 64);
        dw += __shfl_xor(dw, off, 64);
    }
    if (lane == 0) {
        out[r*3 + 0] = cr;
        out[r*3 + 1] = cg;
        out[r*3 + 2] = cb;
        out[n_rays*3 + r] = op;
        out[n_rays*4 + r] = dw / fmaxf(op, 1.1920929e-7f);
    }
}

// ---------------------------------------------------------------------------
extern "C" void kernel_launch(void* const* d_in, const int* in_sizes, int n_in,
                              void* d_out, int out_size, void* d_ws, size_t ws_size,
                              hipStream_t stream)
{
    const float* t_starts    = (const float*)d_in[0];
    const float* t_ends      = (const float*)d_in[1];
    const float* rays_o      = (const float*)d_in[2];
    const float* rays_d      = (const float*)d_in[3];
    const int*   ray_indices = (const int*)  d_in[4];
    const float* tables      = (const float*)d_in[5];
    const float* bw0         = (const float*)d_in[6];
    const float* bw1         = (const float*)d_in[7];
    const float* hw0         = (const float*)d_in[8];
    const float* hw1         = (const float*)d_in[9];
    const float* hw2         = (const float*)d_in[10];
    const float* aabb        = (const float*)d_in[11];

    const int n      = in_sizes[0];        // 524288
    const int n_rays = in_sizes[2] / 3;    // 8192
    const int tbl_n  = in_sizes[5];        // 16*T*2 floats

    float* out = (float*)d_out;
    char*  ws  = (char*)d_ws;

    const size_t tabh_bytes = (size_t)tbl_n * 2;
    const size_t enc_bytes  = (size_t)n * 64;

    ResParams rp;
    const double scale = exp((log(4096.0) - log(16.0)) / 15.0);
    for (int l = 0; l < NLEV; ++l)
        rp.resf[l] = (float)floor(16.0 * pow(scale, (double)l));

    _Float16* tabh = (_Float16*)ws;
    _Float16* encG = (_Float16*)(ws + tabh_bytes);
    float4*   srgb = (float4*)(ws + tabh_bytes + enc_bytes);

    const int n4 = tbl_n / 4;
    k_cvt<<<(n4 + 255)/256, 256, 0, stream>>>(tables, tabh, n4);

    k_hash1<<<(n + 255)/256, 256, 0, stream>>>(
        t_starts, t_ends, rays_o, rays_d, ray_indices, tabh, aabb, encG, n, rp);

    k_mlp<<<(n + 255)/256, 256, 0, stream>>>(
        t_starts, t_ends, rays_o, rays_d, ray_indices, bw0, bw1, hw0, hw1, hw2,
        aabb, encG, srgb, n);
    k_render<<<(n_rays*64 + 255)/256, 256, 0, stream>>>(
        t_starts, t_ends, ray_indices, srgb, out, n, n_rays);
}

// Round 10
// 312.914 us; speedup vs baseline: 1.4275x; 1.0289x over previous
//
#include <hip/hip_runtime.h>
#include <math.h>

#define NLEV 16
#define TBL  (1u << 19)
#define TMASK (TBL - 1u)

typedef _Float16 half2v  __attribute__((ext_vector_type(2)));
typedef _Float16 half4   __attribute__((ext_vector_type(4)));
typedef _Float16 half8   __attribute__((ext_vector_type(8)));
typedef float    floatx4 __attribute__((ext_vector_type(4)));
typedef unsigned int uint2v __attribute__((ext_vector_type(2)));
typedef unsigned int uint4v __attribute__((ext_vector_type(4)));

struct ResParams { float resf[NLEV]; };

__device__ __forceinline__ float sigmoidf(float x) {
    return 1.0f / (1.0f + __expf(-x));
}

__device__ __forceinline__ float2 unpack_h2(unsigned u) {
    union { unsigned u; half2v h; } c; c.u = u;
    return make_float2((float)c.h[0], (float)c.h[1]);
}

// XOR-swizzle for [*][64] f16 buffers: 16B col-blocks permuted by row&7.
__device__ __forceinline__ int swz64(int row, int col) {
    return row * 64 + ((((col >> 3) ^ (row & 7)) << 3) | (col & 7));
}
__device__ __forceinline__ int swz64_blk(int row, int blk) {
    return row * 64 + ((blk ^ (row & 7)) << 3);
}
__device__ __forceinline__ int swz16(int row, int col) {
    return row * 64 + ((((col >> 3) ^ (row & 7)) << 3) | (col & 7));
}
__device__ __forceinline__ int swz16_blk(int row, int blk) {
    return row * 64 + ((blk ^ (row & 7)) << 3);
}

// ---------------------------------------------------------------------------
// Kernel 0: tables f32 -> f16.
// ---------------------------------------------------------------------------
__global__ __launch_bounds__(256) void k_cvt(
    const float* __restrict__ src, _Float16* __restrict__ dst, int n4)
{
    const int i = blockIdx.x * 256 + threadIdx.x;
    if (i >= n4) return;
    const float4 v = ((const float4*)src)[i];
    half4 o; o[0] = (_Float16)v.x; o[1] = (_Float16)v.y;
    o[2] = (_Float16)v.z; o[3] = (_Float16)v.w;
    ((half4*)dst)[i] = o;
}

// ---------------------------------------------------------------------------
// Kernel 1: hash encoding, 1 sample/thread, x-pair 8B loads (round-9 exact:
// VGPR 120, no spill, 144 us — at the L2 request ceiling).
// ---------------------------------------------------------------------------
struct SampPos { float x0, x1, x2; };

__device__ __forceinline__ SampPos load_pos(
    int i, const float* __restrict__ t_starts, const float* __restrict__ t_ends,
    const float* __restrict__ rays_o, const float* __restrict__ rays_d,
    const int* __restrict__ ray_indices,
    float a0, float a1, float a2, float ib0, float ib1, float ib2)
{
    const int   ri = ray_indices[i];
    const float tmid = 0.5f * (t_starts[i] + t_ends[i]);
    const float xn0 = (rays_o[ri*3+0] + rays_d[ri*3+0]*tmid - a0) * ib0;
    const float xn1 = (rays_o[ri*3+1] + rays_d[ri*3+1]*tmid - a1) * ib1;
    const float xn2 = (rays_o[ri*3+2] + rays_d[ri*3+2]*tmid - a2) * ib2;
    SampPos p;
    p.x0 = fminf(fmaxf(xn0, 0.f), 1.f);
    p.x1 = fminf(fmaxf(xn1, 0.f), 1.f);
    p.x2 = fminf(fmaxf(xn2, 0.f), 1.f);
    return p;
}

__global__ __launch_bounds__(256) void k_hash1(
    const float* __restrict__ t_starts, const float* __restrict__ t_ends,
    const float* __restrict__ rays_o,   const float* __restrict__ rays_d,
    const int*   __restrict__ ray_indices,
    const _Float16* __restrict__ tabh,
    const float* __restrict__ aabb,
    _Float16* __restrict__ encG, int n, ResParams rp)
{
    const int i = blockIdx.x * 256 + threadIdx.x;
    if (i >= n) return;

    const float a0 = aabb[0], a1 = aabb[1], a2 = aabb[2];
    const float ib0 = 1.f / (aabb[3] - a0 + 1e-5f);
    const float ib1 = 1.f / (aabb[4] - a1 + 1e-5f);
    const float ib2 = 1.f / (aabb[5] - a2 + 1e-5f);

    const SampPos A = load_pos(i, t_starts, t_ends, rays_o, rays_d, ray_indices,
                               a0, a1, a2, ib0, ib1, ib2);

    union { _Float16 h[32]; uint4v q[4]; } ev;

    #pragma unroll
    for (int l = 0; l < NLEV; ++l) {
        const float resf = rp.resf[l];
        const _Float16* __restrict__ tab = tabh + (size_t)l * (size_t)(TBL * 2u);

        const float p0 = A.x0*resf, p1 = A.x1*resf, p2 = A.x2*resf;
        const float fl0 = floorf(p0), fl1 = floorf(p1), fl2 = floorf(p2);
        const float f0 = p0-fl0, f1 = p1-fl1, f2 = p2-fl2;
        const unsigned i0 = (unsigned)fl0, i1 = (unsigned)fl1, i2 = (unsigned)fl2;
        const unsigned hy0 = i1 * 2654435761u, hy1 = hy0 + 2654435761u;
        const unsigned hz0 = i2 * 805459861u,  hz1 = hz0 + 805459861u;
        const float g0 = 1.f-f0, g1 = 1.f-f1, g2 = 1.f-f2;
        const unsigned ryz[4] = { hy0^hz0, hy0^hz1, hy1^hz0, hy1^hz1 };
        const float    wyz[4] = { g1*g2,   g1*f2,   f1*g2,   f1*f2 };

        unsigned v0[4], v1[4];
        if (!(i0 & 1u)) {        // even: pair {h, h^1} in one aligned 8B load
            #pragma unroll
            for (int c = 0; c < 4; ++c) {
                const unsigned lo = (i0 ^ ryz[c]) & TMASK;
                const uint2v p = *(const uint2v*)(tab + (size_t)(lo & ~1u) * 2u);
                const unsigned sw = lo & 1u;
                v0[c] = sw ? p.y : p.x;
                v1[c] = sw ? p.x : p.y;
            }
        } else {                 // odd: two independent 4B loads
            #pragma unroll
            for (int c = 0; c < 4; ++c) {
                const unsigned lo = (i0        ^ ryz[c]) & TMASK;
                const unsigned hi = ((i0 + 1u) ^ ryz[c]) & TMASK;
                v0[c] = *(const unsigned*)(tab + (size_t)lo * 2u);
                v1[c] = *(const unsigned*)(tab + (size_t)hi * 2u);
            }
        }

        float e0 = 0.f, e1 = 0.f;
        #pragma unroll
        for (int c = 0; c < 4; ++c) {
            const float wlo = g0 * wyz[c], whi = f0 * wyz[c];
            const float2 t0 = unpack_h2(v0[c]), t1 = unpack_h2(v1[c]);
            e0 += wlo * t0.x + whi * t1.x;
            e1 += wlo * t0.y + whi * t1.y;
        }
        ev.h[2*l]   = (_Float16)(e0 * 1024.f);   // *1024: f16-normal range
        ev.h[2*l+1] = (_Float16)(e1 * 1024.f);
    }

    uint4v* dst = (uint4v*)(encG + (size_t)i * 32);
    #pragma unroll
    for (int q = 0; q < 4; ++q) __builtin_nontemporal_store(ev.q[q], dst + q);
}

// ---------------------------------------------------------------------------
// Kernel 1.5: per-ray segment bounds (replaces k_render's binary searches).
// se[2r] = first sample of ray r, se[2r+1] = one-past-last. Rays with no
// samples keep the memset 0,0 -> empty loop -> zero outputs (matches ref).
// ---------------------------------------------------------------------------
__global__ __launch_bounds__(256) void k_bounds(
    const int* __restrict__ ray_indices, int* __restrict__ se, int n)
{
    const int i = blockIdx.x * 256 + threadIdx.x;
    if (i >= n) return;
    const int r = ray_indices[i];
    if (i == 0 || ray_indices[i-1] != r) se[2*r]     = i;
    if (i == n-1 || ray_indices[i+1] != r) se[2*r+1] = i + 1;
}

// ---------------------------------------------------------------------------
// Kernel 2: fused MLP, all five layers via MFMA. NEW: rt tiles processed in
// PAIRS (two independent chains at every dependency point) with per-tile
// swz16 transpose buffers. LDS 52 KB -> 3 blocks/CU.
// gfx950 16x16x32 layouts: A[m=lane&15][k=quad*8+j], B[k][n=lane&15],
// D: row=quad*4+reg, col=lane&15.
// ---------------------------------------------------------------------------
__global__ __launch_bounds__(256) void k_mlp(
    const float* __restrict__ t_starts, const float* __restrict__ t_ends,
    const float* __restrict__ rays_o,   const float* __restrict__ rays_d,
    const int*   __restrict__ ray_indices,
    const float* __restrict__ bw0,  // [32,64]
    const float* __restrict__ bw1,  // [64,16]
    const float* __restrict__ hw0,  // [31,64]
    const float* __restrict__ hw1,  // [64,64]
    const float* __restrict__ hw2,  // [64,3]
    const float* __restrict__ aabb,
    const _Float16* __restrict__ encG,
    float4* __restrict__ srgb, int n)
{
    __shared__ _Float16 sT  [4][2048];      // 16 KB: 2 tiles/wave, swz16
    __shared__ _Float16 sSH [256 * 16];     // 8 KB
    __shared__ _Float16 sHB [256 * 16];     // 8 KB: h[1..15] + zero col 15
    __shared__ _Float16 sW0T[64 * 40];      // 5 KB
    __shared__ _Float16 sW1T[64 * 64];      // 8 KB
    __shared__ _Float16 sBW0T[64 * 32];     // 4 KB
    __shared__ _Float16 sBW1T[16 * 64];     // 2 KB
    __shared__ float    sDT [256];          // 1 KB

    const int t     = threadIdx.x;
    const int gbase = blockIdx.x * 256;

    {
        const int s  = gbase + t;            // n % 256 == 0
        const int ri = ray_indices[s];
        const float ts = t_starts[s], te = t_ends[s];
        const float tmid = 0.5f * (ts + te);
        const float ox = rays_o[ri*3+0], oy = rays_o[ri*3+1], oz = rays_o[ri*3+2];
        const float dx = rays_d[ri*3+0], dy = rays_d[ri*3+1], dz = rays_d[ri*3+2];
        const float a0 = aabb[0], a1 = aabb[1], a2c = aabb[2];
        const float b0 = aabb[3], b1 = aabb[4], b2c = aabb[5];
        const float xn0 = (ox + dx*tmid - a0) / (b0 - a0 + 1e-5f);
        const float xn1 = (oy + dy*tmid - a1) / (b1 - a1 + 1e-5f);
        const float xn2 = (oz + dz*tmid - a2c) / (b2c - a2c + 1e-5f);
        const bool sel = (xn0 > 0.f) && (xn0 < 1.f) && (xn1 > 0.f) && (xn1 < 1.f)
                      && (xn2 > 0.f) && (xn2 < 1.f);
        sDT[t] = sel ? (te - ts) : 0.f;

        const float x = dx, y = dy, z = dz;
        const float x2 = x*x, y2 = y*y, z2 = z*z;
        const float xy = x*y, yz = y*z, xz = x*z;
        float shv[16];
        shv[0]  = 0.28209479177387814f;
        shv[1]  = -0.48860251190291987f * y;
        shv[2]  = 0.48860251190291987f * z;
        shv[3]  = -0.48860251190291987f * x;
        shv[4]  = 1.0925484305920792f * xy;
        shv[5]  = -1.0925484305920792f * yz;
        shv[6]  = 0.94617469575756f * z2 - 0.31539156525252005f;
        shv[7]  = -1.0925484305920792f * xz;
        shv[8]  = 0.5462742152960396f * (x2 - y2);
        shv[9]  = -0.5900435899266435f * y * (3.f*x2 - y2);
        shv[10] = 2.890611442640554f * xy * z;
        shv[11] = -0.4570457994644658f * y * (4.f*z2 - x2 - y2);
        shv[12] = 0.3731763325901154f * z * (2.f*z2 - 3.f*x2 - 3.f*y2);
        shv[13] = -0.4570457994644658f * x * (4.f*z2 - x2 - y2);
        shv[14] = 1.445305721320277f * z * (x2 - y2);
        shv[15] = -0.5900435899266435f * x * (x2 - 3.f*y2);
        #pragma unroll
        for (int k4 = 0; k4 < 4; ++k4) {
            half4 p;
            #pragma unroll
            for (int j = 0; j < 4; ++j) p[j] = (_Float16)shv[k4*4 + j];
            *(half4*)&sSH[t*16 + k4*4] = p;
        }
    }
    {
        const int nidx = t & 63, g = t >> 6;
        #pragma unroll
        for (int i2 = 0; i2 < 8; ++i2) {
            const int k = g*8 + i2;
            const float v = (k < 31) ? hw0[k*64 + nidx] : 0.f;
            sW0T[nidx*40 + k] = (_Float16)v;
        }
        #pragma unroll
        for (int i2 = 0; i2 < 16; ++i2) {
            const int k = g*16 + i2;
            sW1T[swz64(nidx, k)] = (_Float16)hw1[k*64 + nidx];
        }
        #pragma unroll
        for (int i2 = 0; i2 < 8; ++i2) {
            const int k = g*8 + i2;
            sBW0T[nidx*32 + k] = (_Float16)bw0[k*64 + nidx];
        }
    }
    {
        const int nidx = t & 15, g = t >> 4;
        #pragma unroll
        for (int i2 = 0; i2 < 4; ++i2) {
            const int k = g*4 + i2;
            sBW1T[swz16(nidx, k)] = (_Float16)bw1[k*16 + nidx];
        }
    }

    const int lane = t & 63, w = t >> 6;
    const int nn = lane & 15, quad = lane >> 4;
    _Float16* T0 = &sT[w][0];
    _Float16* T1 = &sT[w][1024];

    half8 BH2[2];
    #pragma unroll
    for (int ks = 0; ks < 2; ++ks)
        #pragma unroll
        for (int j = 0; j < 8; ++j) {
            const int k = ks*32 + quad*8 + j;
            BH2[ks][j] = (nn < 3) ? (_Float16)hw2[k*3 + nn] : (_Float16)0.f;
        }

    __syncthreads();

    const int rbase = w * 64;

    #pragma unroll
    for (int p = 0; p < 2; ++p) {
        const int s0 = rbase + p*32;        // tile 0 first sample row
        const int s1 = s0 + 16;             // tile 1
        const int d0 = s0 + quad*4;         // D sample rows
        const int d1 = s1 + quad*4;

        // ---- GEMM1 (transposed, both tiles): hid^T = bw0^T @ enc^T ----
        half8 bE0 = *(const half8*)(encG + (size_t)(gbase + s0 + nn)*32 + quad*8);
        half8 bE1 = *(const half8*)(encG + (size_t)(gbase + s1 + nn)*32 + quad*8);
        #pragma unroll
        for (int ct = 0; ct < 4; ++ct) {
            half8 aW = *(const half8*)&sBW0T[(ct*16 + nn)*32 + quad*8];
            floatx4 a0 = {0.f,0.f,0.f,0.f}, a1 = {0.f,0.f,0.f,0.f};
            a0 = __builtin_amdgcn_mfma_f32_16x16x32_f16(aW, bE0, a0, 0, 0, 0);
            a1 = __builtin_amdgcn_mfma_f32_16x16x32_f16(aW, bE1, a1, 0, 0, 0);
            half4 p0, p1;
            #pragma unroll
            for (int r2 = 0; r2 < 4; ++r2) {
                p0[r2] = (_Float16)fmaxf(a0[r2], 0.f);
                p1[r2] = (_Float16)fmaxf(a1[r2], 0.f);
            }
            *(half4*)&T0[swz16(nn, ct*16 + quad*4)] = p0;
            *(half4*)&T1[swz16(nn, ct*16 + quad*4)] = p1;
        }

        // ---- GEMM2 (both tiles): h = hid @ bw1; sigma broadcast ----
        float sig0[4], sig1[4];
        {
            half8 b20 = *(const half8*)&sBW1T[swz16_blk(nn, quad)];
            half8 b21 = *(const half8*)&sBW1T[swz16_blk(nn, 4 + quad)];
            half8 a200 = *(const half8*)&T0[swz16_blk(nn, quad)];
            half8 a201 = *(const half8*)&T0[swz16_blk(nn, 4 + quad)];
            half8 a210 = *(const half8*)&T1[swz16_blk(nn, quad)];
            half8 a211 = *(const half8*)&T1[swz16_blk(nn, 4 + quad)];
            floatx4 c0 = {0.f,0.f,0.f,0.f}, c1 = {0.f,0.f,0.f,0.f};
            c0 = __builtin_amdgcn_mfma_f32_16x16x32_f16(a200, b20, c0, 0, 0, 0);
            c1 = __builtin_amdgcn_mfma_f32_16x16x32_f16(a210, b20, c1, 0, 0, 0);
            c0 = __builtin_amdgcn_mfma_f32_16x16x32_f16(a201, b21, c0, 0, 0, 0);
            c1 = __builtin_amdgcn_mfma_f32_16x16x32_f16(a211, b21, c1, 0, 0, 0);
            #pragma unroll
            for (int r2 = 0; r2 < 4; ++r2) {
                const float h0v = c0[r2] * (1.f / 1024.f);
                const float h1v = c1[r2] * (1.f / 1024.f);
                const float b0v = __shfl(h0v, lane & 0x30, 64);
                const float b1v = __shfl(h1v, lane & 0x30, 64);
                sig0[r2] = __expf(b0v - 1.f) * sDT[d0 + r2];
                sig1[r2] = __expf(b1v - 1.f) * sDT[d1 + r2];
                if (nn == 0) {
                    sHB[(d0 + r2)*16 + 15] = (_Float16)0.f;
                    sHB[(d1 + r2)*16 + 15] = (_Float16)0.f;
                } else {
                    sHB[(d0 + r2)*16 + (nn - 1)] = (_Float16)h0v;
                    sHB[(d1 + r2)*16 + (nn - 1)] = (_Float16)h1v;
                }
            }
        }

        // ---- GEMM3 (transposed, both tiles): a2^T = hw0^T @ hh^T ----
        half8 sh0 = *(const half8*)&sSH[(s0 + nn)*16 + (quad & 1)*8];
        half8 hb0 = *(const half8*)&sHB[(s0 + nn)*16 + (quad & 1)*8];
        half8 sh1 = *(const half8*)&sSH[(s1 + nn)*16 + (quad & 1)*8];
        half8 hb1 = *(const half8*)&sHB[(s1 + nn)*16 + (quad & 1)*8];
        half8 f30 = (quad < 2) ? sh0 : hb0;
        half8 f31 = (quad < 2) ? sh1 : hb1;
        #pragma unroll
        for (int ct = 0; ct < 4; ++ct) {
            half8 aW = *(const half8*)&sW0T[(ct*16 + nn)*40 + quad*8];
            floatx4 a0 = {0.f,0.f,0.f,0.f}, a1 = {0.f,0.f,0.f,0.f};
            a0 = __builtin_amdgcn_mfma_f32_16x16x32_f16(aW, f30, a0, 0, 0, 0);
            a1 = __builtin_amdgcn_mfma_f32_16x16x32_f16(aW, f31, a1, 0, 0, 0);
            half4 p0, p1;
            #pragma unroll
            for (int r2 = 0; r2 < 4; ++r2) {
                p0[r2] = (_Float16)fmaxf(a0[r2], 0.f);
                p1[r2] = (_Float16)fmaxf(a1[r2], 0.f);
            }
            *(half4*)&T0[swz16(nn, ct*16 + quad*4)] = p0;
            *(half4*)&T1[swz16(nn, ct*16 + quad*4)] = p1;
        }

        // ---- GEMM4 (transposed, both tiles): a3^T = hw1^T @ a2^T ----
        half8 af00 = *(const half8*)&T0[swz16_blk(nn, quad)];
        half8 af01 = *(const half8*)&T0[swz16_blk(nn, 4 + quad)];
        half8 af10 = *(const half8*)&T1[swz16_blk(nn, quad)];
        half8 af11 = *(const half8*)&T1[swz16_blk(nn, 4 + quad)];
        #pragma unroll
        for (int ct = 0; ct < 4; ++ct) {
            half8 aW0 = *(const half8*)&sW1T[swz64_blk(ct*16 + nn, quad)];
            half8 aW1 = *(const half8*)&sW1T[swz64_blk(ct*16 + nn, 4 + quad)];
            floatx4 a0 = {0.f,0.f,0.f,0.f}, a1 = {0.f,0.f,0.f,0.f};
            a0 = __builtin_amdgcn_mfma_f32_16x16x32_f16(aW0, af00, a0, 0, 0, 0);
            a1 = __builtin_amdgcn_mfma_f32_16x16x32_f16(aW0, af10, a1, 0, 0, 0);
            a0 = __builtin_amdgcn_mfma_f32_16x16x32_f16(aW1, af01, a0, 0, 0, 0);
            a1 = __builtin_amdgcn_mfma_f32_16x16x32_f16(aW1, af11, a1, 0, 0, 0);
            half4 p0, p1;
            #pragma unroll
            for (int r2 = 0; r2 < 4; ++r2) {
                p0[r2] = (_Float16)fmaxf(a0[r2], 0.f);
                p1[r2] = (_Float16)fmaxf(a1[r2], 0.f);
            }
            *(half4*)&T0[swz16(nn, ct*16 + quad*4)] = p0;
            *(half4*)&T1[swz16(nn, ct*16 + quad*4)] = p1;
        }

        // ---- GEMM5 (both tiles): rgb = a3 @ hw2 ----
        {
            half8 a500 = *(const half8*)&T0[swz16_blk(nn, quad)];
            half8 a501 = *(const half8*)&T0[swz16_blk(nn, 4 + quad)];
            half8 a510 = *(const half8*)&T1[swz16_blk(nn, quad)];
            half8 a511 = *(const half8*)&T1[swz16_blk(nn, 4 + quad)];
            floatx4 c0 = {0.f,0.f,0.f,0.f}, c1 = {0.f,0.f,0.f,0.f};
            c0 = __builtin_amdgcn_mfma_f32_16x16x32_f16(a500, BH2[0], c0, 0, 0, 0);
            c1 = __builtin_amdgcn_mfma_f32_16x16x32_f16(a510, BH2[0], c1, 0, 0, 0);
            c0 = __builtin_amdgcn_mfma_f32_16x16x32_f16(a501, BH2[1], c0, 0, 0, 0);
            c1 = __builtin_amdgcn_mfma_f32_16x16x32_f16(a511, BH2[1], c1, 0, 0, 0);
            #pragma unroll
            for (int r2 = 0; r2 < 4; ++r2) {
                float* bp0 = (float*)&srgb[gbase + d0 + r2];
                float* bp1 = (float*)&srgb[gbase + d1 + r2];
                if (nn < 3) {
                    bp0[1 + nn] = sigmoidf(c0[r2]);
                    bp1[1 + nn] = sigmoidf(c1[r2]);
                } else if (nn == 3) {
                    bp0[0] = sig0[r2];
                    bp1[0] = sig1[r2];
                }
            }
        }
    }
}

// ---------------------------------------------------------------------------
// Kernel 3: wave-per-ray compositing; segment bounds come precomputed.
// ---------------------------------------------------------------------------
__global__ __launch_bounds__(256) void k_render(
    const float* __restrict__ t_starts, const float* __restrict__ t_ends,
    const int*   __restrict__ se,
    const float4* __restrict__ srgb,
    float* __restrict__ out, int n_rays)
{
    const int wid  = (blockIdx.x * 256 + threadIdx.x) >> 6;
    const int lane = threadIdx.x & 63;
    if (wid >= n_rays) return;
    const int r = wid;

    const int start = se[2*r];
    const int end   = se[2*r + 1];

    float S = 0.f, cr = 0.f, cg = 0.f, cb = 0.f, op = 0.f, dw = 0.f;
    for (int j0 = start; j0 < end; j0 += 64) {
        const int j = j0 + lane;
        float s = 0.f, R = 0.f, G = 0.f, B = 0.f, tm = 0.f;
        if (j < end) {
            const float4 v = srgb[j];
            s = v.x; R = v.y; G = v.z; B = v.w;
            tm = 0.5f * (t_starts[j] + t_ends[j]);
        }
        float incl = s;
        #pragma unroll
        for (int off = 1; off < 64; off <<= 1) {
            const float tv = __shfl_up(incl, off, 64);
            if (lane >= off) incl += tv;
        }
        const float excl  = incl - s;
        const float trans = __expf(-(S + excl));
        const float alpha = 1.f - __expf(-s);
        const float wgt   = trans * alpha;
        cr += wgt * R; cg += wgt * G; cb += wgt * B;
        op += wgt;     dw += wgt * tm;
        S += __shfl(incl, 63, 64);
    }
    #pragma unroll
    for (int off = 1; off < 64; off <<= 1) {
        cr += __shfl_xor(cr, off, 64);
        cg += __shfl_xor(cg, off, 64);
        cb += __shfl_xor(cb, off, 64);
        op += __shfl_xor(op, off, 64);
        dw += __shfl_xor(dw, off, 64);
    }
    if (lane == 0) {
        out[r*3 + 0] = cr;
        out[r*3 + 1] = cg;
        out[r*3 + 2] = cb;
        out[n_rays*3 + r] = op;
        out[n_rays*4 + r] = dw / fmaxf(op, 1.1920929e-7f);
    }
}

// ---------------------------------------------------------------------------
extern "C" void kernel_launch(void* const* d_in, const int* in_sizes, int n_in,
                              void* d_out, int out_size, void* d_ws, size_t ws_size,
                              hipStream_t stream)
{
    const float* t_starts    = (const float*)d_in[0];
    const float* t_ends      = (const float*)d_in[1];
    const float* rays_o      = (const float*)d_in[2];
    const float* rays_d      = (const float*)d_in[3];
    const int*   ray_indices = (const int*)  d_in[4];
    const float* tables      = (const float*)d_in[5];
    const float* bw0         = (const float*)d_in[6];
    const float* bw1         = (const float*)d_in[7];
    const float* hw0         = (const float*)d_in[8];
    const float* hw1         = (const float*)d_in[9];
    const float* hw2         = (const float*)d_in[10];
    const float* aabb        = (const float*)d_in[11];

    const int n      = in_sizes[0];        // 524288
    const int n_rays = in_sizes[2] / 3;    // 8192
    const int tbl_n  = in_sizes[5];        // 16*T*2 floats

    float* out = (float*)d_out;
    char*  ws  = (char*)d_ws;

    const size_t tabh_bytes = (size_t)tbl_n * 2;
    const size_t enc_bytes  = (size_t)n * 64;
    const size_t srgb_bytes = (size_t)n * 16;

    ResParams rp;
    const double scale = exp((log(4096.0) - log(16.0)) / 15.0);
    for (int l = 0; l < NLEV; ++l)
        rp.resf[l] = (float)floor(16.0 * pow(scale, (double)l));

    _Float16* tabh = (_Float16*)ws;
    _Float16* encG = (_Float16*)(ws + tabh_bytes);
    float4*   srgb = (float4*)(ws + tabh_bytes + enc_bytes);
    int*      se   = (int*)(ws + tabh_bytes + enc_bytes + srgb_bytes);

    const int n4 = tbl_n / 4;
    k_cvt<<<(n4 + 255)/256, 256, 0, stream>>>(tables, tabh, n4);

    hipMemsetAsync(se, 0, (size_t)n_rays * 2 * sizeof(int), stream);
    k_bounds<<<(n + 255)/256, 256, 0, stream>>>(ray_indices, se, n);

    k_hash1<<<(n + 255)/256, 256, 0, stream>>>(
        t_starts, t_ends, rays_o, rays_d, ray_indices, tabh, aabb, encG, n, rp);

    k_mlp<<<(n + 255)/256, 256, 0, stream>>>(
        t_starts, t_ends, rays_o, rays_d, ray_indices, bw0, bw1, hw0, hw1, hw2,
        aabb, encG, srgb, n);

    k_render<<<(n_rays*64 + 255)/256, 256, 0, stream>>>(
        t_starts, t_ends, se, srgb, out, n_rays);
}